// Round 1
// baseline (313.303 us; speedup 1.0000x reference)
//
#include <hip/hip_runtime.h>
#include <math.h>

// Problem constants (from reference setup_inputs): B=1024, N=200, E=128, fp32.
constexpr int Bc = 1024;
constexpr int Nc = 200;
constexpr int Ec = 128;

// R2: latency-bound (VALUBusy 9%, HBM 15%, occ 37%). Grid 1024 x 256thr gave
// only 16 waves/CU (half the slots at VGPR=64). Go to 512-thread blocks:
// 16 groups x 32 lanes, ROWS=5 -> 3 passes (80+80+40 rows). 4 blocks/CU x
// 8 waves = 32 waves/CU -> 2x in-flight loads, and per-wave serialized pass
// count drops 5 -> 3.
constexpr int THREADS = 512;
constexpr int GROUPS  = THREADS / 32;                       // 16
constexpr int ROWS    = 5;                                  // rows per group per pass
constexpr int PASSES  = (Nc + GROUPS * ROWS - 1) / (GROUPS * ROWS);  // 3

// __launch_bounds__(512, 8): 8 waves/EU min -> caps VGPR at 64 (same body
// compiled to exactly 64 VGPRs at 256 threads, so no spill expected).
__global__ __launch_bounds__(THREADS, 8) void fused_dist_softmax(
    const float* __restrict__ q,      // (B,E)
    const float* __restrict__ q_p,    // (B,E)
    const float* __restrict__ m,      // (B,N,E)
    const float* __restrict__ m_c,    // (B,N,E)
    const float* __restrict__ A1,     // (E,1) -> flat E
    const float* __restrict__ A2,     // (E,1) -> flat E
    const float* __restrict__ biases, // (B,N)
    const float* __restrict__ mask,   // (B,N)
    float* __restrict__ out)          // (B,N)
{
    const int b    = blockIdx.x;
    const int tid  = threadIdx.x;
    const int hw   = tid >> 5;   // group id 0..15
    const int lane = tid & 31;   // lane within group
    const int e0   = lane * 4;

    __shared__ float xs[Nc];      // -(att * mask)  per n
    __shared__ float os[Nc];      // out_dist * mask per n
    __shared__ float red_s[16];   // cross-wave reduction scratch (8 max + 8 sum)

    // Per-lane chunks of q, q_p, A1, A2 (each lane owns 4 consecutive e's).
    const float4 qv  = *reinterpret_cast<const float4*>(q   + (size_t)b * Ec + e0);
    const float4 qpv = *reinterpret_cast<const float4*>(q_p + (size_t)b * Ec + e0);
    const float4 a1v = *reinterpret_cast<const float4*>(A1  + e0);
    const float4 a2v = *reinterpret_cast<const float4*>(A2  + e0);

    const float* mb  = m   + (size_t)b * Nc * Ec;
    const float* mcb = m_c + (size_t)b * Nc * Ec;

    for (int pass = 0; pass < PASSES; ++pass) {
        const int n0 = pass * (GROUPS * ROWS) + hw * ROWS;
        if (n0 < Nc) {   // pass 2: only groups 0..7 have rows (160..199)
            // Issue all 10 loads first: max outstanding vmcnt per lane.
            float4 mv[ROWS], mcv[ROWS];
#pragma unroll
            for (int r = 0; r < ROWS; ++r) {
                mv[r]  = *reinterpret_cast<const float4*>(mb  + (size_t)(n0 + r) * Ec + e0);
                mcv[r] = *reinterpret_cast<const float4*>(mcb + (size_t)(n0 + r) * Ec + e0);
            }

            float s_att[ROWS], s_out[ROWS];
#pragma unroll
            for (int r = 0; r < ROWS; ++r) {
                float sa = 0.f, so = 0.f;
#define COMP(c) {                                                        \
                float t1 = (qv.c  - mv[r].c)  * a1v.c;  sa = fmaf(t1, t1, sa); \
                float t2 = (qpv.c - mv[r].c)  * a2v.c;  sa = fmaf(t2, t2, sa); \
                float u1 = (qv.c  - mcv[r].c) * a1v.c;  so = fmaf(u1, u1, so); \
                float u2 = (qpv.c - mcv[r].c) * a2v.c;  so = fmaf(u2, u2, so); }
                COMP(x) COMP(y) COMP(z) COMP(w)
#undef COMP
                s_att[r] = sa;
                s_out[r] = so;
            }

            // 10 interleaved shuffle-reduce chains (xor masks <=16 stay within
            // each 32-lane half of the wave64).
#pragma unroll
            for (int off = 16; off > 0; off >>= 1) {
#pragma unroll
                for (int r = 0; r < ROWS; ++r) {
                    s_att[r] += __shfl_xor(s_att[r], off);
                    s_out[r] += __shfl_xor(s_out[r], off);
                }
            }

            if (lane == 0) {
#pragma unroll
                for (int r = 0; r < ROWS; ++r) {
                    const int n = n0 + r;
                    const float bb = biases[(size_t)b * Nc + n];
                    const float mk = mask[(size_t)b * Nc + n];
                    // att_dist = d1 + bias + d2 + bias = s_att + 2*bias
                    xs[n] = -(s_att[r] + 2.f * bb) * mk;   // softmax argument
                    os[n] = (s_out[r] + 2.f * bb) * mk;    // out_dist * mask
                }
            }
        }
    }
    __syncthreads();

    // Block-wide softmax over the 200 entries. Thread tid owns n = tid.
    // Waves 4..7 (tid >= 256) carry -INF / 0 and participate harmlessly.
    float x = (tid < Nc) ? xs[tid] : -INFINITY;

    // max
    float wmax = x;
#pragma unroll
    for (int off = 32; off > 0; off >>= 1)
        wmax = fmaxf(wmax, __shfl_xor(wmax, off));
    if ((tid & 63) == 0) red_s[tid >> 6] = wmax;
    __syncthreads();
    float gmax = red_s[0];
#pragma unroll
    for (int w = 1; w < THREADS / 64; ++w) gmax = fmaxf(gmax, red_s[w]);

    // sum of exp
    const float ex = (tid < Nc) ? expf(x - gmax) : 0.f;
    float wsum = ex;
#pragma unroll
    for (int off = 32; off > 0; off >>= 1)
        wsum += __shfl_xor(wsum, off);
    if ((tid & 63) == 0) red_s[8 + (tid >> 6)] = wsum;
    __syncthreads();
    float gsum = 0.f;
#pragma unroll
    for (int w = 0; w < THREADS / 64; ++w) gsum += red_s[8 + w];

    if (tid < Nc) {
        out[(size_t)b * Nc + tid] = os[tid] * (ex / gsum);
    }
}

extern "C" void kernel_launch(void* const* d_in, const int* in_sizes, int n_in,
                              void* d_out, int out_size, void* d_ws, size_t ws_size,
                              hipStream_t stream) {
    const float* q      = (const float*)d_in[0];
    const float* q_p    = (const float*)d_in[1];
    const float* m      = (const float*)d_in[2];
    const float* m_c    = (const float*)d_in[3];
    const float* A1     = (const float*)d_in[4];
    const float* A2     = (const float*)d_in[5];
    const float* biases = (const float*)d_in[6];
    const float* mask   = (const float*)d_in[7];
    float* out = (float*)d_out;

    fused_dist_softmax<<<Bc, THREADS, 0, stream>>>(q, q_p, m, m_c, A1, A2, biases, mask, out);
}

// Round 2
// 237.955 us; speedup vs baseline: 1.3166x; 1.3166x over previous
//
#include <hip/hip_runtime.h>
#include <math.h>

// Problem constants (from reference setup_inputs): B=1024, N=200, E=128, fp32.
constexpr int Bc = 1024;
constexpr int Nc = 200;
constexpr int Ec = 128;

// R2 post-mortem: __launch_bounds__(512, 8) capped VGPR at 32 -> 212 MB of
// scratch spill traffic (WRITE_SIZE), useful BW fell to 1.3 TB/s. The
// occupancy mechanism itself worked (81% resident). Fix: minWavesPerEU=4
// -> VGPR cap 64 (the body needs exactly 64; zero spill at 256 threads).
// At VGPR=64 the HW still allows 8 waves/EU, so residency can reach
// 32 waves/CU without the spill.
constexpr int THREADS = 512;
constexpr int GROUPS  = THREADS / 32;                       // 16
constexpr int ROWS    = 5;                                  // rows per group per pass
constexpr int PASSES  = (Nc + GROUPS * ROWS - 1) / (GROUPS * ROWS);  // 3

__global__ __launch_bounds__(THREADS, 4) void fused_dist_softmax(
    const float* __restrict__ q,      // (B,E)
    const float* __restrict__ q_p,    // (B,E)
    const float* __restrict__ m,      // (B,N,E)
    const float* __restrict__ m_c,    // (B,N,E)
    const float* __restrict__ A1,     // (E,1) -> flat E
    const float* __restrict__ A2,     // (E,1) -> flat E
    const float* __restrict__ biases, // (B,N)
    const float* __restrict__ mask,   // (B,N)
    float* __restrict__ out)          // (B,N)
{
    const int b    = blockIdx.x;
    const int tid  = threadIdx.x;
    const int hw   = tid >> 5;   // group id 0..15
    const int lane = tid & 31;   // lane within group
    const int e0   = lane * 4;

    __shared__ float xs[Nc];      // -(att * mask)  per n
    __shared__ float os[Nc];      // out_dist * mask per n
    __shared__ float red_s[16];   // cross-wave reduction scratch (8 max + 8 sum)

    // Per-lane chunks of q, q_p, A1, A2 (each lane owns 4 consecutive e's).
    const float4 qv  = *reinterpret_cast<const float4*>(q   + (size_t)b * Ec + e0);
    const float4 qpv = *reinterpret_cast<const float4*>(q_p + (size_t)b * Ec + e0);
    const float4 a1v = *reinterpret_cast<const float4*>(A1  + e0);
    const float4 a2v = *reinterpret_cast<const float4*>(A2  + e0);

    const float* mb  = m   + (size_t)b * Nc * Ec;
    const float* mcb = m_c + (size_t)b * Nc * Ec;

    for (int pass = 0; pass < PASSES; ++pass) {
        const int n0 = pass * (GROUPS * ROWS) + hw * ROWS;
        if (n0 < Nc) {   // pass 2: only groups 0..7 have rows (160..199)
            // Issue all 10 loads first: max outstanding vmcnt per lane.
            float4 mv[ROWS], mcv[ROWS];
#pragma unroll
            for (int r = 0; r < ROWS; ++r) {
                mv[r]  = *reinterpret_cast<const float4*>(mb  + (size_t)(n0 + r) * Ec + e0);
                mcv[r] = *reinterpret_cast<const float4*>(mcb + (size_t)(n0 + r) * Ec + e0);
            }

            float s_att[ROWS], s_out[ROWS];
#pragma unroll
            for (int r = 0; r < ROWS; ++r) {
                float sa = 0.f, so = 0.f;
#define COMP(c) {                                                        \
                float t1 = (qv.c  - mv[r].c)  * a1v.c;  sa = fmaf(t1, t1, sa); \
                float t2 = (qpv.c - mv[r].c)  * a2v.c;  sa = fmaf(t2, t2, sa); \
                float u1 = (qv.c  - mcv[r].c) * a1v.c;  so = fmaf(u1, u1, so); \
                float u2 = (qpv.c - mcv[r].c) * a2v.c;  so = fmaf(u2, u2, so); }
                COMP(x) COMP(y) COMP(z) COMP(w)
#undef COMP
                s_att[r] = sa;
                s_out[r] = so;
            }

            // 10 interleaved shuffle-reduce chains (xor masks <=16 stay within
            // each 32-lane half of the wave64).
#pragma unroll
            for (int off = 16; off > 0; off >>= 1) {
#pragma unroll
                for (int r = 0; r < ROWS; ++r) {
                    s_att[r] += __shfl_xor(s_att[r], off);
                    s_out[r] += __shfl_xor(s_out[r], off);
                }
            }

            if (lane == 0) {
#pragma unroll
                for (int r = 0; r < ROWS; ++r) {
                    const int n = n0 + r;
                    const float bb = biases[(size_t)b * Nc + n];
                    const float mk = mask[(size_t)b * Nc + n];
                    // att_dist = d1 + bias + d2 + bias = s_att + 2*bias
                    xs[n] = -(s_att[r] + 2.f * bb) * mk;   // softmax argument
                    os[n] = (s_out[r] + 2.f * bb) * mk;    // out_dist * mask
                }
            }
        }
    }
    __syncthreads();

    // Block-wide softmax over the 200 entries. Thread tid owns n = tid.
    // Waves 4..7 (tid >= 256) carry -INF / 0 and participate harmlessly.
    float x = (tid < Nc) ? xs[tid] : -INFINITY;

    // max
    float wmax = x;
#pragma unroll
    for (int off = 32; off > 0; off >>= 1)
        wmax = fmaxf(wmax, __shfl_xor(wmax, off));
    if ((tid & 63) == 0) red_s[tid >> 6] = wmax;
    __syncthreads();
    float gmax = red_s[0];
#pragma unroll
    for (int w = 1; w < THREADS / 64; ++w) gmax = fmaxf(gmax, red_s[w]);

    // sum of exp
    const float ex = (tid < Nc) ? expf(x - gmax) : 0.f;
    float wsum = ex;
#pragma unroll
    for (int off = 32; off > 0; off >>= 1)
        wsum += __shfl_xor(wsum, off);
    if ((tid & 63) == 0) red_s[8 + (tid >> 6)] = wsum;
    __syncthreads();
    float gsum = 0.f;
#pragma unroll
    for (int w = 0; w < THREADS / 64; ++w) gsum += red_s[8 + w];

    if (tid < Nc) {
        out[(size_t)b * Nc + tid] = os[tid] * (ex / gsum);
    }
}

extern "C" void kernel_launch(void* const* d_in, const int* in_sizes, int n_in,
                              void* d_out, int out_size, void* d_ws, size_t ws_size,
                              hipStream_t stream) {
    const float* q      = (const float*)d_in[0];
    const float* q_p    = (const float*)d_in[1];
    const float* m      = (const float*)d_in[2];
    const float* m_c    = (const float*)d_in[3];
    const float* A1     = (const float*)d_in[4];
    const float* A2     = (const float*)d_in[5];
    const float* biases = (const float*)d_in[6];
    const float* mask   = (const float*)d_in[7];
    float* out = (float*)d_out;

    fused_dist_softmax<<<Bc, THREADS, 0, stream>>>(q, q_p, m, m_c, A1, A2, biases, mask, out);
}

// Round 3
// 236.177 us; speedup vs baseline: 1.3266x; 1.0075x over previous
//
#include <hip/hip_runtime.h>
#include <math.h>

// Problem constants: B=1024, N=200, E=128, fp32.
constexpr int Bc = 1024;
constexpr int Nc = 200;
constexpr int Ec = 128;

// R3: R0/R2 showed occupancy stuck ~33-37% with grid == exactly 4 blocks/CU:
// no backfill queue, so the time-averaged residency is dominated by the
// ramp-down tail (L3-hit blocks finish ~2x faster than HBM-miss blocks).
// Split the work fine-grained: 5 blocks per batch (40 rows each), 5120 blocks
// total -> 20 block-slots queued per CU, continuous backfill. Softmax moves
// to a tiny second kernel (reads 1.6 MB).
constexpr int ROWS    = 5;                 // rows per 32-lane group
constexpr int GROUPS  = 8;                 // 256 threads / 32
constexpr int NSPLIT  = 5;                 // blocks per batch (5*40 = 200 rows)

__global__ __launch_bounds__(256, 4) void dist_phase(
    const float* __restrict__ q,      // (B,E)
    const float* __restrict__ q_p,    // (B,E)
    const float* __restrict__ m,      // (B,N,E)
    const float* __restrict__ m_c,    // (B,N,E)
    const float* __restrict__ A1,     // (E)
    const float* __restrict__ A2,     // (E)
    const float* __restrict__ biases, // (B,N)
    const float* __restrict__ mask,   // (B,N)
    float* __restrict__ xs_ws,        // (B,N) softmax arguments -> workspace
    float* __restrict__ out)          // (B,N) out_dist*mask (scaled later by k2)
{
    const int j    = blockIdx.x;     // 0..NSPLIT-1  (which 40-row slice)
    const int b    = blockIdx.y;     // batch
    const int tid  = threadIdx.x;
    const int hw   = tid >> 5;       // group id 0..7
    const int lane = tid & 31;
    const int e0   = lane * 4;

    const int n0 = j * (GROUPS * ROWS) + hw * ROWS;

    // Per-lane chunks of q, q_p, A1, A2.
    const float4 qv  = *reinterpret_cast<const float4*>(q   + (size_t)b * Ec + e0);
    const float4 qpv = *reinterpret_cast<const float4*>(q_p + (size_t)b * Ec + e0);
    const float4 a1v = *reinterpret_cast<const float4*>(A1  + e0);
    const float4 a2v = *reinterpret_cast<const float4*>(A2  + e0);

    const float* mb  = m   + (size_t)b * Nc * Ec;
    const float* mcb = m_c + (size_t)b * Nc * Ec;

    // Issue all 10 loads first: max outstanding vmcnt per lane.
    float4 mv[ROWS], mcv[ROWS];
#pragma unroll
    for (int r = 0; r < ROWS; ++r) {
        mv[r]  = *reinterpret_cast<const float4*>(mb  + (size_t)(n0 + r) * Ec + e0);
        mcv[r] = *reinterpret_cast<const float4*>(mcb + (size_t)(n0 + r) * Ec + e0);
    }

    float s_att[ROWS], s_out[ROWS];
#pragma unroll
    for (int r = 0; r < ROWS; ++r) {
        float sa = 0.f, so = 0.f;
#define COMP(c) {                                                        \
        float t1 = (qv.c  - mv[r].c)  * a1v.c;  sa = fmaf(t1, t1, sa); \
        float t2 = (qpv.c - mv[r].c)  * a2v.c;  sa = fmaf(t2, t2, sa); \
        float u1 = (qv.c  - mcv[r].c) * a1v.c;  so = fmaf(u1, u1, so); \
        float u2 = (qpv.c - mcv[r].c) * a2v.c;  so = fmaf(u2, u2, so); }
        COMP(x) COMP(y) COMP(z) COMP(w)
#undef COMP
        s_att[r] = sa;
        s_out[r] = so;
    }

    // 10 interleaved shuffle-reduce chains (xor <=16 stays in the 32-lane half).
#pragma unroll
    for (int off = 16; off > 0; off >>= 1) {
#pragma unroll
        for (int r = 0; r < ROWS; ++r) {
            s_att[r] += __shfl_xor(s_att[r], off);
            s_out[r] += __shfl_xor(s_out[r], off);
        }
    }

    if (lane == 0) {
#pragma unroll
        for (int r = 0; r < ROWS; ++r) {
            const int n = n0 + r;
            const float bb = biases[(size_t)b * Nc + n];
            const float mk = mask[(size_t)b * Nc + n];
            // att_dist = d1 + bias + d2 + bias = s_att + 2*bias
            xs_ws[(size_t)b * Nc + n] = -(s_att[r] + 2.f * bb) * mk;
            out  [(size_t)b * Nc + n] =  (s_out[r] + 2.f * bb) * mk;
        }
    }
}

// One 256-thread block per batch: softmax over the 200 entries, scale os.
__global__ __launch_bounds__(256, 4) void softmax_phase(
    const float* __restrict__ xs_ws,  // (B,N)
    float* __restrict__ out)          // (B,N) in: os, out: os * softmax
{
    const int b   = blockIdx.x;
    const int tid = threadIdx.x;

    __shared__ float red_s[8];  // 4 max + 4 sum

    const float x  = (tid < Nc) ? xs_ws[(size_t)b * Nc + tid] : -INFINITY;
    const float os = (tid < Nc) ? out  [(size_t)b * Nc + tid] : 0.f;

    // max
    float wmax = x;
#pragma unroll
    for (int off = 32; off > 0; off >>= 1)
        wmax = fmaxf(wmax, __shfl_xor(wmax, off));
    if ((tid & 63) == 0) red_s[tid >> 6] = wmax;
    __syncthreads();
    const float gmax = fmaxf(fmaxf(red_s[0], red_s[1]), fmaxf(red_s[2], red_s[3]));

    // sum of exp
    const float ex = (tid < Nc) ? expf(x - gmax) : 0.f;
    float wsum = ex;
#pragma unroll
    for (int off = 32; off > 0; off >>= 1)
        wsum += __shfl_xor(wsum, off);
    if ((tid & 63) == 0) red_s[4 + (tid >> 6)] = wsum;
    __syncthreads();
    const float gsum = (red_s[4] + red_s[5]) + (red_s[6] + red_s[7]);

    if (tid < Nc) {
        out[(size_t)b * Nc + tid] = os * (ex / gsum);
    }
}

extern "C" void kernel_launch(void* const* d_in, const int* in_sizes, int n_in,
                              void* d_out, int out_size, void* d_ws, size_t ws_size,
                              hipStream_t stream) {
    const float* q      = (const float*)d_in[0];
    const float* q_p    = (const float*)d_in[1];
    const float* m      = (const float*)d_in[2];
    const float* m_c    = (const float*)d_in[3];
    const float* A1     = (const float*)d_in[4];
    const float* A2     = (const float*)d_in[5];
    const float* biases = (const float*)d_in[6];
    const float* mask   = (const float*)d_in[7];
    float* out   = (float*)d_out;
    float* xs_ws = (float*)d_ws;     // needs B*N*4 = 800 KB of workspace

    dim3 grid1(NSPLIT, Bc, 1);
    dist_phase<<<grid1, 256, 0, stream>>>(q, q_p, m, m_c, A1, A2, biases, mask,
                                          xs_ws, out);
    softmax_phase<<<Bc, 256, 0, stream>>>(xs_ws, out);
}

// Round 4
// 236.054 us; speedup vs baseline: 1.3272x; 1.0005x over previous
//
#include <hip/hip_runtime.h>
#include <math.h>

// Problem constants: B=1024, N=200, E=128, fp32.
constexpr int Bc = 1024;
constexpr int Nc = 200;
constexpr int Ec = 128;

// R4: R3 fixed occupancy (64%) via 5120-block split, but the compiler shrank
// VGPR to 32 and broke the 10-load burst (per-wave MLP fell ~3x) -> perf flat.
// Fix: asm memory barrier after the load burst. Loads cannot be sunk past a
// memory-clobber asm, so all 10 float4 results stay live -> VGPR ~64, which
// still allows 8 waves/EU (512-reg file / 64). First time both levers
// (waves/CU x in-flight loads/wave) are high simultaneously.
constexpr int ROWS    = 5;                 // rows per 32-lane group
constexpr int GROUPS  = 8;                 // 256 threads / 32
constexpr int NSPLIT  = 5;                 // blocks per batch (5*40 = 200 rows)

__global__ __launch_bounds__(256, 4) void dist_phase(
    const float* __restrict__ q,      // (B,E)
    const float* __restrict__ q_p,    // (B,E)
    const float* __restrict__ m,      // (B,N,E)
    const float* __restrict__ m_c,    // (B,N,E)
    const float* __restrict__ A1,     // (E)
    const float* __restrict__ A2,     // (E)
    const float* __restrict__ biases, // (B,N)
    const float* __restrict__ mask,   // (B,N)
    float* __restrict__ xs_ws,        // (B,N) softmax arguments -> workspace
    float* __restrict__ out)          // (B,N) out_dist*mask (scaled later by k2)
{
    const int j    = blockIdx.x;     // 0..NSPLIT-1  (which 40-row slice)
    const int b    = blockIdx.y;     // batch
    const int tid  = threadIdx.x;
    const int hw   = tid >> 5;       // group id 0..7
    const int lane = tid & 31;
    const int e0   = lane * 4;

    const int n0 = j * (GROUPS * ROWS) + hw * ROWS;

    // Per-lane chunks of q, q_p, A1, A2.
    const float4 qv  = *reinterpret_cast<const float4*>(q   + (size_t)b * Ec + e0);
    const float4 qpv = *reinterpret_cast<const float4*>(q_p + (size_t)b * Ec + e0);
    const float4 a1v = *reinterpret_cast<const float4*>(A1  + e0);
    const float4 a2v = *reinterpret_cast<const float4*>(A2  + e0);

    const float* mb  = m   + (size_t)b * Nc * Ec;
    const float* mcb = m_c + (size_t)b * Nc * Ec;

    // Issue all 10 loads; the asm memory barrier below pins them all before
    // any compute -> 10 outstanding vmem ops per lane, ~56 live VGPRs.
    float4 mv[ROWS], mcv[ROWS];
#pragma unroll
    for (int r = 0; r < ROWS; ++r) {
        mv[r]  = *reinterpret_cast<const float4*>(mb  + (size_t)(n0 + r) * Ec + e0);
        mcv[r] = *reinterpret_cast<const float4*>(mcb + (size_t)(n0 + r) * Ec + e0);
    }
    asm volatile("" ::: "memory");   // do not split the load burst

    float s_att[ROWS], s_out[ROWS];
#pragma unroll
    for (int r = 0; r < ROWS; ++r) {
        float sa = 0.f, so = 0.f;
#define COMP(c) {                                                        \
        float t1 = (qv.c  - mv[r].c)  * a1v.c;  sa = fmaf(t1, t1, sa); \
        float t2 = (qpv.c - mv[r].c)  * a2v.c;  sa = fmaf(t2, t2, sa); \
        float u1 = (qv.c  - mcv[r].c) * a1v.c;  so = fmaf(u1, u1, so); \
        float u2 = (qpv.c - mcv[r].c) * a2v.c;  so = fmaf(u2, u2, so); }
        COMP(x) COMP(y) COMP(z) COMP(w)
#undef COMP
        s_att[r] = sa;
        s_out[r] = so;
    }

    // 10 interleaved shuffle-reduce chains (xor <=16 stays in the 32-lane half).
#pragma unroll
    for (int off = 16; off > 0; off >>= 1) {
#pragma unroll
        for (int r = 0; r < ROWS; ++r) {
            s_att[r] += __shfl_xor(s_att[r], off);
            s_out[r] += __shfl_xor(s_out[r], off);
        }
    }

    if (lane == 0) {
#pragma unroll
        for (int r = 0; r < ROWS; ++r) {
            const int n = n0 + r;
            const float bb = biases[(size_t)b * Nc + n];
            const float mk = mask[(size_t)b * Nc + n];
            // att_dist = d1 + bias + d2 + bias = s_att + 2*bias
            xs_ws[(size_t)b * Nc + n] = -(s_att[r] + 2.f * bb) * mk;
            out  [(size_t)b * Nc + n] =  (s_out[r] + 2.f * bb) * mk;
        }
    }
}

// One 256-thread block per batch: softmax over the 200 entries, scale os.
__global__ __launch_bounds__(256, 4) void softmax_phase(
    const float* __restrict__ xs_ws,  // (B,N)
    float* __restrict__ out)          // (B,N) in: os, out: os * softmax
{
    const int b   = blockIdx.x;
    const int tid = threadIdx.x;

    __shared__ float red_s[8];  // 4 max + 4 sum

    const float x  = (tid < Nc) ? xs_ws[(size_t)b * Nc + tid] : -INFINITY;
    const float os = (tid < Nc) ? out  [(size_t)b * Nc + tid] : 0.f;

    // max
    float wmax = x;
#pragma unroll
    for (int off = 32; off > 0; off >>= 1)
        wmax = fmaxf(wmax, __shfl_xor(wmax, off));
    if ((tid & 63) == 0) red_s[tid >> 6] = wmax;
    __syncthreads();
    const float gmax = fmaxf(fmaxf(red_s[0], red_s[1]), fmaxf(red_s[2], red_s[3]));

    // sum of exp
    const float ex = (tid < Nc) ? expf(x - gmax) : 0.f;
    float wsum = ex;
#pragma unroll
    for (int off = 32; off > 0; off >>= 1)
        wsum += __shfl_xor(wsum, off);
    if ((tid & 63) == 0) red_s[4 + (tid >> 6)] = wsum;
    __syncthreads();
    const float gsum = (red_s[4] + red_s[5]) + (red_s[6] + red_s[7]);

    if (tid < Nc) {
        out[(size_t)b * Nc + tid] = os * (ex / gsum);
    }
}

extern "C" void kernel_launch(void* const* d_in, const int* in_sizes, int n_in,
                              void* d_out, int out_size, void* d_ws, size_t ws_size,
                              hipStream_t stream) {
    const float* q      = (const float*)d_in[0];
    const float* q_p    = (const float*)d_in[1];
    const float* m      = (const float*)d_in[2];
    const float* m_c    = (const float*)d_in[3];
    const float* A1     = (const float*)d_in[4];
    const float* A2     = (const float*)d_in[5];
    const float* biases = (const float*)d_in[6];
    const float* mask   = (const float*)d_in[7];
    float* out   = (float*)d_out;
    float* xs_ws = (float*)d_ws;     // needs B*N*4 = 800 KB of workspace

    dim3 grid1(NSPLIT, Bc, 1);
    dist_phase<<<grid1, 256, 0, stream>>>(q, q_p, m, m_c, A1, A2, biases, mask,
                                          xs_ws, out);
    softmax_phase<<<Bc, 256, 0, stream>>>(xs_ws, out);
}

// Round 5
// 221.319 us; speedup vs baseline: 1.4156x; 1.0666x over previous
//
#include <hip/hip_runtime.h>
#include <math.h>

// Problem constants: B=1024, N=200, E=128, fp32.
constexpr int Bc = 1024;
constexpr int Nc = 200;
constexpr int Ec = 128;

// R5: two mechanisms, separable by counters.
// (1) R4's "memory"-clobber pin was a no-op (VGPR stayed 32): the clobber
//     orders memory ops, not the dependent FMAs, so the compiler re-interleaved
//     uses between loads (~2-3 in flight). Fix: ONE volatile asm consuming all
//     10 loaded vectors as "+v" operands -> all loads precede it, all compute
//     follows it, single vmcnt(0) wait with 10 loads outstanding.
// (2) Every config so far caps at 2.7-3.0 TB/s effective while dense float4
//     copy does 6.3. Steady state shows ~50% L3 hits (FETCH pinned at 106 of
//     210 MB: the working set thrashes the 256 MB L3) -> the DRAM-visible
//     stream is a half-density 64B-line scatter with poor page locality.
//     Data is single-use per dispatch: mark m/m_c loads non-temporal so lines
//     don't retain in L3 and the DRAM stream is dense sequential.
constexpr int ROWS    = 5;                 // rows per 32-lane group
constexpr int GROUPS  = 8;                 // 256 threads / 32
constexpr int NSPLIT  = 5;                 // blocks per batch (5*40 = 200 rows)

typedef float v4f __attribute__((ext_vector_type(4)));

__global__ __launch_bounds__(256, 4) void dist_phase(
    const float* __restrict__ q,      // (B,E)
    const float* __restrict__ q_p,    // (B,E)
    const float* __restrict__ m,      // (B,N,E)
    const float* __restrict__ m_c,    // (B,N,E)
    const float* __restrict__ A1,     // (E)
    const float* __restrict__ A2,     // (E)
    const float* __restrict__ biases, // (B,N)
    const float* __restrict__ mask,   // (B,N)
    float* __restrict__ xs_ws,        // (B,N) softmax arguments -> workspace
    float* __restrict__ out)          // (B,N) out_dist*mask (scaled later by k2)
{
    const int j    = blockIdx.x;     // 0..NSPLIT-1  (which 40-row slice)
    const int b    = blockIdx.y;     // batch
    const int tid  = threadIdx.x;
    const int hw   = tid >> 5;       // group id 0..7
    const int lane = tid & 31;
    const int e0   = lane * 4;

    const int n0 = j * (GROUPS * ROWS) + hw * ROWS;

    // Per-lane chunks of q, q_p, A1, A2 (small, reused across blocks: cached).
    const v4f qv  = *reinterpret_cast<const v4f*>(q   + (size_t)b * Ec + e0);
    const v4f qpv = *reinterpret_cast<const v4f*>(q_p + (size_t)b * Ec + e0);
    const v4f a1v = *reinterpret_cast<const v4f*>(A1  + e0);
    const v4f a2v = *reinterpret_cast<const v4f*>(A2  + e0);

    const float* mb  = m   + (size_t)b * Nc * Ec;
    const float* mcb = m_c + (size_t)b * Nc * Ec;

    // Issue all 10 loads, non-temporal (single-use streaming data).
    v4f mv[ROWS], mcv[ROWS];
#pragma unroll
    for (int r = 0; r < ROWS; ++r) {
        mv[r]  = __builtin_nontemporal_load(
                     reinterpret_cast<const v4f*>(mb  + (size_t)(n0 + r) * Ec + e0));
        mcv[r] = __builtin_nontemporal_load(
                     reinterpret_cast<const v4f*>(mcb + (size_t)(n0 + r) * Ec + e0));
    }
    // Value-pin: this asm consumes ALL loaded vectors, so every load must be
    // issued before it and every use scheduled after it -> one vmcnt(0) wait
    // with 10 float4 loads in flight per lane.
    asm volatile("" : "+v"(mv[0]), "+v"(mv[1]), "+v"(mv[2]), "+v"(mv[3]), "+v"(mv[4]),
                      "+v"(mcv[0]), "+v"(mcv[1]), "+v"(mcv[2]), "+v"(mcv[3]), "+v"(mcv[4]));

    float s_att[ROWS], s_out[ROWS];
#pragma unroll
    for (int r = 0; r < ROWS; ++r) {
        float sa = 0.f, so = 0.f;
#pragma unroll
        for (int c = 0; c < 4; ++c) {
            float t1 = (qv[c]  - mv[r][c])  * a1v[c];  sa = fmaf(t1, t1, sa);
            float t2 = (qpv[c] - mv[r][c])  * a2v[c];  sa = fmaf(t2, t2, sa);
            float u1 = (qv[c]  - mcv[r][c]) * a1v[c];  so = fmaf(u1, u1, so);
            float u2 = (qpv[c] - mcv[r][c]) * a2v[c];  so = fmaf(u2, u2, so);
        }
        s_att[r] = sa;
        s_out[r] = so;
    }

    // 10 interleaved shuffle-reduce chains (xor <=16 stays in the 32-lane half).
#pragma unroll
    for (int off = 16; off > 0; off >>= 1) {
#pragma unroll
        for (int r = 0; r < ROWS; ++r) {
            s_att[r] += __shfl_xor(s_att[r], off);
            s_out[r] += __shfl_xor(s_out[r], off);
        }
    }

    if (lane == 0) {
#pragma unroll
        for (int r = 0; r < ROWS; ++r) {
            const int n = n0 + r;
            const float bb = biases[(size_t)b * Nc + n];
            const float mk = mask[(size_t)b * Nc + n];
            // att_dist = d1 + bias + d2 + bias = s_att + 2*bias
            xs_ws[(size_t)b * Nc + n] = -(s_att[r] + 2.f * bb) * mk;
            out  [(size_t)b * Nc + n] =  (s_out[r] + 2.f * bb) * mk;
        }
    }
}

// One 256-thread block per batch: softmax over the 200 entries, scale os.
__global__ __launch_bounds__(256, 4) void softmax_phase(
    const float* __restrict__ xs_ws,  // (B,N)
    float* __restrict__ out)          // (B,N) in: os, out: os * softmax
{
    const int b   = blockIdx.x;
    const int tid = threadIdx.x;

    __shared__ float red_s[8];  // 4 max + 4 sum

    const float x  = (tid < Nc) ? xs_ws[(size_t)b * Nc + tid] : -INFINITY;
    const float os = (tid < Nc) ? out  [(size_t)b * Nc + tid] : 0.f;

    // max
    float wmax = x;
#pragma unroll
    for (int off = 32; off > 0; off >>= 1)
        wmax = fmaxf(wmax, __shfl_xor(wmax, off));
    if ((tid & 63) == 0) red_s[tid >> 6] = wmax;
    __syncthreads();
    const float gmax = fmaxf(fmaxf(red_s[0], red_s[1]), fmaxf(red_s[2], red_s[3]));

    // sum of exp
    const float ex = (tid < Nc) ? expf(x - gmax) : 0.f;
    float wsum = ex;
#pragma unroll
    for (int off = 32; off > 0; off >>= 1)
        wsum += __shfl_xor(wsum, off);
    if ((tid & 63) == 0) red_s[4 + (tid >> 6)] = wsum;
    __syncthreads();
    const float gsum = (red_s[4] + red_s[5]) + (red_s[6] + red_s[7]);

    if (tid < Nc) {
        out[(size_t)b * Nc + tid] = os * (ex / gsum);
    }
}

extern "C" void kernel_launch(void* const* d_in, const int* in_sizes, int n_in,
                              void* d_out, int out_size, void* d_ws, size_t ws_size,
                              hipStream_t stream) {
    const float* q      = (const float*)d_in[0];
    const float* q_p    = (const float*)d_in[1];
    const float* m      = (const float*)d_in[2];
    const float* m_c    = (const float*)d_in[3];
    const float* A1     = (const float*)d_in[4];
    const float* A2     = (const float*)d_in[5];
    const float* biases = (const float*)d_in[6];
    const float* mask   = (const float*)d_in[7];
    float* out   = (float*)d_out;
    float* xs_ws = (float*)d_ws;     // needs B*N*4 = 800 KB of workspace

    dim3 grid1(NSPLIT, Bc, 1);
    dist_phase<<<grid1, 256, 0, stream>>>(q, q_p, m, m_c, A1, A2, biases, mask,
                                          xs_ws, out);
    softmax_phase<<<Bc, 256, 0, stream>>>(xs_ws, out);
}